// Round 11
// baseline (756.234 us; speedup 1.0000x reference)
//
#include <hip/hip_runtime.h>

#define NN 50000
#define EE 800000
#define GG 512
#define NP 50048   // NN padded to multiple of 64
#define EB 3125    // edge blocks of 256
#define SCB 196    // scan blocks of 256 covering NN

typedef short bf16x8 __attribute__((ext_vector_type(8)));
typedef float floatx4 __attribute__((ext_vector_type(4)));

__device__ inline unsigned short f2b(float f) {
    unsigned u = __float_as_uint(f);
    unsigned r = (u + 0x7fffu + ((u >> 16) & 1u)) >> 16;
    return (unsigned short)r;
}
__device__ inline float b2f(unsigned short b) {
    return __uint_as_float(((unsigned)b) << 16);
}

// ---------------- fused conversion: x and ef -> bf16 ----------------

__global__ void conv_all(const float* __restrict__ x, unsigned short* __restrict__ xb, long n8x,
                         const float* __restrict__ ef, unsigned short* __restrict__ efB, long n8e) {
    long i = (long)blockIdx.x * blockDim.x + threadIdx.x;
    const float* s;
    unsigned short* d;
    long idx;
    if (i < n8x) { s = x; d = xb; idx = i; }
    else if (i < n8x + n8e) { s = ef; d = efB; idx = i - n8x; }
    else return;
    float4 a = ((const float4*)s)[2 * idx];
    float4 b = ((const float4*)s)[2 * idx + 1];
    unsigned short o[8] = {f2b(a.x), f2b(a.y), f2b(a.z), f2b(a.w),
                           f2b(b.x), f2b(b.y), f2b(b.z), f2b(b.w)};
    ((uint4*)d)[idx] = *(uint4*)o;
}

// ---------------- fused weight transpose: 12 matrices in one launch ----------------

struct TpD { const float* W; unsigned short* WT; int K, F, Kp, rowOff; };
struct TpTab { TpD d[12]; };

__global__ void tp_all(TpTab t) {
    TpD dd = t.d[blockIdx.y];
    int f = blockIdx.x;
    if (f >= dd.F) return;
    for (int k = threadIdx.x; k < dd.Kp; k += blockDim.x)
        dd.WT[(size_t)f * dd.Kp + k] =
            (k < dd.K) ? f2b(dd.W[(size_t)(dd.rowOff + k) * dd.F + f]) : (unsigned short)0;
}

// ---------------- sort pipeline ----------------

__global__ void hist_cnt(const int* __restrict__ dst, int* __restrict__ hist,
                         const int* __restrict__ gid, float* __restrict__ gcnt) {
    int b = blockIdx.x;
    if (b < EB) {
        int e = b * 256 + threadIdx.x;
        if (e < EE) atomicAdd(&hist[dst[e]], 1);
    } else {
        int n = (b - EB) * 256 + threadIdx.x;
        if (n < NN) atomicAdd(&gcnt[gid[n]], 1.0f);
    }
}

// 3-phase exclusive scan of hist -> cursor
__global__ void scanA(const int* __restrict__ hist, int* __restrict__ bsum) {
    __shared__ int sb[256];
    int idx = blockIdx.x * 256 + threadIdx.x;
    sb[threadIdx.x] = (idx < NN) ? hist[idx] : 0;
    __syncthreads();
    for (int off = 128; off > 0; off >>= 1) {
        if (threadIdx.x < off) sb[threadIdx.x] += sb[threadIdx.x + off];
        __syncthreads();
    }
    if (threadIdx.x == 0) bsum[blockIdx.x] = sb[0];
}

__global__ void scanB(const int* __restrict__ bsum, int* __restrict__ boff) {
    __shared__ int sb[256];
    int t = threadIdx.x;
    int v = (t < SCB) ? bsum[t] : 0;
    sb[t] = v;
    __syncthreads();
    for (int off = 1; off < 256; off <<= 1) {
        int u = (t >= off) ? sb[t - off] : 0;
        __syncthreads();
        sb[t] += u;
        __syncthreads();
    }
    if (t < SCB) boff[t] = sb[t] - v;
}

__global__ void scanC(const int* __restrict__ hist, const int* __restrict__ boff,
                      int* __restrict__ cursor) {
    __shared__ int sb[256];
    int t = threadIdx.x;
    int idx = blockIdx.x * 256 + t;
    int v = (idx < NN) ? hist[idx] : 0;
    sb[t] = v;
    __syncthreads();
    for (int off = 1; off < 256; off <<= 1) {
        int u = (t >= off) ? sb[t - off] : 0;
        __syncthreads();
        sb[t] += u;
        __syncthreads();
    }
    if (idx < NN) cursor[idx] = boff[blockIdx.x] + sb[t] - v;
}

// scatter + ef gather fused: coalesced read of efB[e], scattered write to efS[p]
__global__ void scatter_kernel(const int* __restrict__ src, const int* __restrict__ dst,
                               int* __restrict__ cursor, const unsigned short* __restrict__ efB,
                               int* __restrict__ srcS, int* __restrict__ dstS,
                               unsigned short* __restrict__ efS) {
    int e = blockIdx.x * blockDim.x + threadIdx.x;
    if (e < EE) {
        int d = dst[e];
        int p = atomicAdd(&cursor[d], 1);
        srcS[p] = src[e];
        dstS[p] = d;
        const uint4* s = (const uint4*)&efB[(size_t)e * 16];
        uint4* dd = (uint4*)&efS[(size_t)p * 16];
        dd[0] = s[0];
        dd[1] = s[1];
    }
}

__global__ void finalize_init(const int* __restrict__ hist, float* __restrict__ invdeg,
                              float* __restrict__ gcnt, float* __restrict__ score,
                              const float* __restrict__ bc0, const float* __restrict__ bc1,
                              const float* __restrict__ bc2, const float* __restrict__ bc3) {
    int i = blockIdx.x * blockDim.x + threadIdx.x;
    if (i < NN) invdeg[i] = 1.0f / fmaxf((float)hist[i], 1.0f);
    if (i < GG) {
        float c = gcnt[i];
        gcnt[i] = 1.0f / fmaxf(c, 1.0f);
        score[i] = (c > 0.0f) ? (bc0[0] + bc1[0] + bc2[0] + bc3[0]) : 0.0f;
    }
}

// ---------------- nodeP: P = feat @ WmX ----------------

template<int FIN, int F>
__global__ __launch_bounds__(256)
void nodeP(const unsigned short* __restrict__ featB, const unsigned short* __restrict__ WxT,
           unsigned short* __restrict__ P)
{
    const int tid = threadIdx.x;
    const int w   = tid >> 6;
    const int l   = tid & 63;
    const int l16 = l & 15;
    const int q   = l >> 4;
    const int cb  = blockIdx.y * 64;
    const int nb  = blockIdx.x * 64;
    const int row = nb + w * 16 + l16;

    floatx4 acc[4];
    #pragma unroll
    for (int nt = 0; nt < 4; ++nt) acc[nt] = (floatx4){0.f, 0.f, 0.f, 0.f};

    #pragma unroll
    for (int kb = 0; kb < FIN; kb += 32) {
        bf16x8 a = *(const bf16x8*)&featB[(size_t)row * FIN + kb + q * 8];
        #pragma unroll
        for (int nt = 0; nt < 4; ++nt) {
            bf16x8 b = *(const bf16x8*)&WxT[(size_t)(cb + nt * 16 + l16) * FIN + kb + q * 8];
            acc[nt] = __builtin_amdgcn_mfma_f32_16x16x32_bf16(a, b, acc[nt], 0, 0, 0);
        }
    }

    #pragma unroll
    for (int nt = 0; nt < 4; ++nt)
        #pragma unroll
        for (int r = 0; r < 4; ++r) {
            int ro = nb + w * 16 + q * 4 + r;
            P[(size_t)ro * F + cb + nt * 16 + l16] = f2b(acc[nt][r]);
        }
}

// ---------------- edge kernel: relu(efS@WmE + P[src] + bm) -> per-wave segmented
// reduce over sorted dst. CW=128 (2 cols/lane) or 64 (scalar). Per-strip P-gather
// issued BEFORE the MFMAs. Half-transpose (8 rows at a time) halves LDS ->
// 8 blocks/CU (32 waves). Wave-private LDS: NO barriers. ----------------

template<int F>
__global__ __launch_bounds__(256)
void edge_q(const unsigned short* __restrict__ efS,
            const int* __restrict__ srcS, const int* __restrict__ dstS,
            const unsigned short* __restrict__ WeT, const unsigned short* __restrict__ P,
            const float* __restrict__ bm, float* __restrict__ agg)
{
    constexpr int CW  = (F >= 128) ? 128 : 64;  // cols per wave
    constexpr int WPG = F / CW;                 // waves per 64-edge subtile (1 or 2)
    constexpr int NT  = CW / 16;
    constexpr int EPB = 64 * (4 / WPG);         // edges per block (256 or 128)
    constexpr int RS  = (CW == 128) ? 132 : 68; // red row stride (bank-safe)

    __shared__ __align__(16) float red[4][8 * RS];   // 8 rows only (half-transpose)

    const int tid = threadIdx.x;
    const int w   = tid >> 6;
    const int l   = tid & 63;
    const int l16 = l & 15;
    const int q   = l >> 4;
    const int sub = w / WPG;
    const int cb  = (w % WPG) * CW;
    const int be  = blockIdx.x * EPB + sub * 64;

    const int dreg = dstS[be + l];
    const int sreg = srcS[be + l];

    const bf16x8 ZV = {0, 0, 0, 0, 0, 0, 0, 0};

    // B fragments: WmE^T [F][32] (rows 16..31 zero-padded)
    bf16x8 bfr[NT];
    #pragma unroll
    for (int nt = 0; nt < NT; ++nt)
        bfr[nt] = *(const bf16x8*)&WeT[(size_t)(cb + nt * 16 + l16) * 32 + q * 8];

    if constexpr (CW == 128) {
        float2 bmv;
        bmv.x = bm[cb + 2 * l];
        bmv.y = bm[cb + 2 * l + 1];

        int cur_d = -1;
        float2 csum = {0.f, 0.f};
        bool from_start = false;

        #pragma unroll
        for (int mt = 0; mt < 4; ++mt) {
            // P-gathers issued first: max distance to their consumption in the scan
            unsigned pvv[16];
            #pragma unroll
            for (int r = 0; r < 16; ++r) {
                int sr = __shfl(sreg, mt * 16 + r);
                pvv[r] = *(const unsigned*)&P[(size_t)sr * F + cb + 2 * l];
            }

            bf16x8 a = ZV;
            if (q < 2) a = *(const bf16x8*)&efS[(size_t)(be + mt * 16 + l16) * 16 + q * 8];
            floatx4 acc[NT];
            #pragma unroll
            for (int nt = 0; nt < NT; ++nt)
                acc[nt] = __builtin_amdgcn_mfma_f32_16x16x32_bf16(
                    a, bfr[nt], (floatx4){0.f, 0.f, 0.f, 0.f}, 0, 0, 0);

            // two half-transposes: rows 0-7 held by q<2, rows 8-15 by q>=2
            #pragma unroll
            for (int h = 0; h < 2; ++h) {
                if ((q >> 1) == h) {
                    #pragma unroll
                    for (int nt = 0; nt < NT; ++nt)
                        #pragma unroll
                        for (int r4 = 0; r4 < 4; ++r4)
                            red[w][((q & 1) * 4 + r4) * RS + nt * 16 + l16] = acc[nt][r4];
                }
                #pragma unroll
                for (int r = 0; r < 8; ++r) {
                    int rr = h * 8 + r;
                    int gr = mt * 16 + rr;
                    int d = __shfl(dreg, gr);
                    float2 qv = *(const float2*)&red[w][r * RS + 2 * l];
                    unsigned pw = pvv[rr];
                    float2 v;
                    v.x = fmaxf(qv.x + __uint_as_float(pw << 16)         + bmv.x, 0.f);
                    v.y = fmaxf(qv.y + __uint_as_float(pw & 0xffff0000u) + bmv.y, 0.f);
                    if (gr == 0) {
                        cur_d = d; csum = v; from_start = true;
                    } else if (d != cur_d) {
                        float* ap = &agg[(size_t)cur_d * F + cb + 2 * l];
                        if (from_start) { atomicAdd(ap, csum.x); atomicAdd(ap + 1, csum.y); }
                        else            { *(float2*)ap = csum; }
                        cur_d = d; csum = v; from_start = false;
                    } else {
                        csum.x += v.x; csum.y += v.y;
                    }
                }
            }
        }
        float* ap = &agg[(size_t)cur_d * F + cb + 2 * l];
        atomicAdd(ap, csum.x);
        atomicAdd(ap + 1, csum.y);
    } else {
        const float bmv = bm[cb + l];

        int cur_d = -1;
        float csum = 0.f;
        bool from_start = false;

        #pragma unroll
        for (int mt = 0; mt < 4; ++mt) {
            float pv[16];
            #pragma unroll
            for (int r = 0; r < 16; ++r) {
                int sr = __shfl(sreg, mt * 16 + r);
                pv[r] = b2f(P[(size_t)sr * F + cb + l]);
            }

            bf16x8 a = ZV;
            if (q < 2) a = *(const bf16x8*)&efS[(size_t)(be + mt * 16 + l16) * 16 + q * 8];
            floatx4 acc[NT];
            #pragma unroll
            for (int nt = 0; nt < NT; ++nt)
                acc[nt] = __builtin_amdgcn_mfma_f32_16x16x32_bf16(
                    a, bfr[nt], (floatx4){0.f, 0.f, 0.f, 0.f}, 0, 0, 0);

            #pragma unroll
            for (int h = 0; h < 2; ++h) {
                if ((q >> 1) == h) {
                    #pragma unroll
                    for (int nt = 0; nt < NT; ++nt)
                        #pragma unroll
                        for (int r4 = 0; r4 < 4; ++r4)
                            red[w][((q & 1) * 4 + r4) * RS + nt * 16 + l16] = acc[nt][r4];
                }
                #pragma unroll
                for (int r = 0; r < 8; ++r) {
                    int rr = h * 8 + r;
                    int gr = mt * 16 + rr;
                    int d = __shfl(dreg, gr);
                    float v = fmaxf(red[w][r * RS + l] + pv[rr] + bmv, 0.f);
                    if (gr == 0) {
                        cur_d = d; csum = v; from_start = true;
                    } else if (d != cur_d) {
                        float* ap = &agg[(size_t)cur_d * F + cb + l];
                        if (from_start) atomicAdd(ap, csum);
                        else *ap = csum;
                        cur_d = d; csum = v; from_start = false;
                    } else {
                        csum += v;
                    }
                }
            }
        }
        atomicAdd(&agg[(size_t)cur_d * F + cb + l], csum);
    }
}

// ---------------- node MFMA GEMM: feat' = relu(agg*invdeg + feat@Ws + bs);
// per-node classifier dot accumulated into rd[n] ----------------

template<int FIN, int F>
__global__ __launch_bounds__(256)
void node_mfma(const unsigned short* __restrict__ featB, const float* __restrict__ agg,
               const unsigned short* __restrict__ WsT, const float* __restrict__ bs,
               const float* __restrict__ Wc, const float* __restrict__ invdeg,
               unsigned short* __restrict__ fout, float* __restrict__ rd)
{
    const int tid = threadIdx.x;
    const int w   = tid >> 6;
    const int l   = tid & 63;
    const int l16 = l & 15;
    const int q   = l >> 4;
    const int cb  = blockIdx.y * 64;
    const int nb  = blockIdx.x * 64;
    const int row = nb + w * 16 + l16;

    floatx4 acc[4];
    #pragma unroll
    for (int nt = 0; nt < 4; ++nt) acc[nt] = (floatx4){0.f, 0.f, 0.f, 0.f};

    #pragma unroll
    for (int kb = 0; kb < FIN; kb += 32) {
        bf16x8 a = *(const bf16x8*)&featB[(size_t)row * FIN + kb + q * 8];
        #pragma unroll
        for (int nt = 0; nt < 4; ++nt) {
            bf16x8 b = *(const bf16x8*)&WsT[(size_t)(cb + nt * 16 + l16) * FIN + kb + q * 8];
            acc[nt] = __builtin_amdgcn_mfma_f32_16x16x32_bf16(a, b, acc[nt], 0, 0, 0);
        }
    }

    float wcv[4], bsv[4];
    #pragma unroll
    for (int nt = 0; nt < 4; ++nt) {
        wcv[nt] = Wc[cb + nt * 16 + l16];
        bsv[nt] = bs[cb + nt * 16 + l16];
    }

    #pragma unroll
    for (int r = 0; r < 4; ++r) {
        int n = nb + w * 16 + q * 4 + r;
        bool valid = n < NN;
        float idg = valid ? invdeg[n] : 0.f;
        float s = 0.f;
        #pragma unroll
        for (int nt = 0; nt < 4; ++nt) {
            int col = cb + nt * 16 + l16;
            float av = valid ? agg[(size_t)n * F + col] : 0.f;
            float v = fmaxf(acc[nt][r] + av * idg + bsv[nt], 0.f);
            if (valid) fout[(size_t)n * F + col] = f2b(v);
            s += v * wcv[nt];
        }
        s += __shfl_xor(s, 1);
        s += __shfl_xor(s, 2);
        s += __shfl_xor(s, 4);
        s += __shfl_xor(s, 8);
        if (valid && l16 == 0) atomicAdd(&rd[n], s);
    }
}

// ---------------- final: score[g] += invg[g] * segmented-sum(rd) over sorted gid ----------------

__global__ void score_reduce(const float* __restrict__ rd, const int* __restrict__ gid,
                             const float* __restrict__ invg, float* __restrict__ score) {
    int n = blockIdx.x * blockDim.x + threadIdx.x;
    int l = threadIdx.x & 63;
    bool valid = n < NN;
    int g = valid ? gid[n] : -1;
    float v = valid ? rd[n] : 0.f;
    #pragma unroll
    for (int off = 1; off < 64; off <<= 1) {
        float vo = __shfl_up(v, off);
        int go = __shfl_up(g, off);
        if (l >= off && go == g) v += vo;
    }
    int gn = __shfl_down(g, 1);
    bool tail = (l == 63) || (gn != g);
    if (valid && tail) atomicAdd(&score[g], v * invg[g]);
}

// ---------------- host ----------------

extern "C" void kernel_launch(void* const* d_in, const int* in_sizes, int n_in,
                              void* d_out, int out_size, void* d_ws, size_t ws_size,
                              hipStream_t stream) {
    const float* x   = (const float*)d_in[0];
    const float* ef  = (const float*)d_in[1];
    const int*   src = (const int*)d_in[2];
    const int*   dst = (const int*)d_in[3];
    const int*   gid = (const int*)d_in[4];
    const float *Wm[4], *bm[4], *Ws[4], *bs[4], *Wc[4], *bc[4];
    for (int i = 0; i < 4; ++i) {
        Wm[i] = (const float*)d_in[5 + 6 * i];
        bm[i] = (const float*)d_in[6 + 6 * i];
        Ws[i] = (const float*)d_in[7 + 6 * i];
        bs[i] = (const float*)d_in[8 + 6 * i];
        Wc[i] = (const float*)d_in[9 + 6 * i];
        bc[i] = (const float*)d_in[10 + 6 * i];
    }

    char* w = (char*)d_ws;
    float* agg = (float*)w;                  w += (size_t)NN * 256 * 4;
    unsigned short* xb  = (unsigned short*)w; w += (size_t)NP * 32 * 2;
    unsigned short* f1  = (unsigned short*)w; w += (size_t)NP * 64 * 2;
    unsigned short* f2  = (unsigned short*)w; w += (size_t)NP * 128 * 2;
    unsigned short* f3  = (unsigned short*)w; w += (size_t)NP * 128 * 2;
    unsigned short* f4  = (unsigned short*)w; w += (size_t)NP * 256 * 2;
    unsigned short* P   = (unsigned short*)w; w += (size_t)NP * 256 * 2;
    unsigned short* efB = (unsigned short*)w; w += (size_t)EE * 16 * 2;
    unsigned short* efS = (unsigned short*)w; w += (size_t)EE * 16 * 2;
    unsigned short* WxT0 = (unsigned short*)w; w += (size_t)64 * 32 * 2;
    unsigned short* WxT1 = (unsigned short*)w; w += (size_t)128 * 64 * 2;
    unsigned short* WxT2 = (unsigned short*)w; w += (size_t)128 * 128 * 2;
    unsigned short* WxT3 = (unsigned short*)w; w += (size_t)256 * 128 * 2;
    unsigned short* WeT0 = (unsigned short*)w; w += (size_t)64 * 32 * 2;
    unsigned short* WeT1 = (unsigned short*)w; w += (size_t)128 * 32 * 2;
    unsigned short* WeT2 = (unsigned short*)w; w += (size_t)128 * 32 * 2;
    unsigned short* WeT3 = (unsigned short*)w; w += (size_t)256 * 32 * 2;
    unsigned short* WsT0 = (unsigned short*)w; w += (size_t)64 * 32 * 2;
    unsigned short* WsT1 = (unsigned short*)w; w += (size_t)128 * 64 * 2;
    unsigned short* WsT2 = (unsigned short*)w; w += (size_t)128 * 128 * 2;
    unsigned short* WsT3 = (unsigned short*)w; w += (size_t)256 * 128 * 2;
    float* invdeg = (float*)w;               w += (size_t)NN * 4;
    float* invg   = (float*)w;               w += (size_t)GG * 4;
    float* rd     = (float*)w;               w += (size_t)NN * 4;
    int* srcS   = (int*)w;                   w += (size_t)EE * 4;
    int* dstS   = (int*)w;                   w += (size_t)EE * 4;
    int* hist   = (int*)w;                   w += (size_t)(NN + 1) * 4;
    int* bsum   = (int*)w;                   w += (size_t)SCB * 4;
    int* boff   = (int*)w;                   w += (size_t)SCB * 4;
    int* cursor = (int*)w;                   w += (size_t)NN * 4;
    float* score = (float*)d_out;

    // ---- conversions / weight prep (fused launches) ----
    const long n8x = (long)NN * 32 / 8, n8e = (long)EE * 16 / 8;
    conv_all<<<(n8x + n8e + 255) / 256, 256, 0, stream>>>(x, xb, n8x, ef, efB, n8e);

    TpTab tt;
    tt.d[0]  = {Wm[0], WxT0,  32,  64,  32,   0};
    tt.d[1]  = {Wm[1], WxT1,  64, 128,  64,   0};
    tt.d[2]  = {Wm[2], WxT2, 128, 128, 128,   0};
    tt.d[3]  = {Wm[3], WxT3, 128, 256, 128,   0};
    tt.d[4]  = {Wm[0], WeT0,  16,  64,  32,  32};
    tt.d[5]  = {Wm[1], WeT1,  16, 128,  32,  64};
    tt.d[6]  = {Wm[2], WeT2,  16, 128,  32, 128};
    tt.d[7]  = {Wm[3], WeT3,  16, 256,  32, 128};
    tt.d[8]  = {Ws[0], WsT0,  32,  64,  32,   0};
    tt.d[9]  = {Ws[1], WsT1,  64, 128,  64,   0};
    tt.d[10] = {Ws[2], WsT2, 128, 128, 128,   0};
    tt.d[11] = {Ws[3], WsT3, 128, 256, 128,   0};
    tp_all<<<dim3(256, 12), 256, 0, stream>>>(tt);

    // ---- sort edges by dst ----
    hipMemsetAsync(hist, 0, (NN + 1) * sizeof(int), stream);
    hipMemsetAsync(invg, 0, GG * sizeof(float), stream);
    hipMemsetAsync(rd, 0, NN * sizeof(float), stream);
    hist_cnt<<<EB + SCB, 256, 0, stream>>>(dst, hist, gid, invg);
    scanA<<<SCB, 256, 0, stream>>>(hist, bsum);
    scanB<<<1, 256, 0, stream>>>(bsum, boff);
    scanC<<<SCB, 256, 0, stream>>>(hist, boff, cursor);
    finalize_init<<<SCB, 256, 0, stream>>>(hist, invdeg, invg, score,
                                           bc[0], bc[1], bc[2], bc[3]);
    scatter_kernel<<<EB, 256, 0, stream>>>(src, dst, cursor, efB, srcS, dstS, efS);

    const int NB = NP / 64;            // 782

    // layer 0: fin=32, f=64  (CW=64, EPB=256)
    nodeP<32, 64><<<dim3(NB, 1), 256, 0, stream>>>(xb, WxT0, P);
    hipMemsetAsync(agg, 0, (size_t)NN * 64 * 4, stream);
    edge_q<64><<<EB, 256, 0, stream>>>(efS, srcS, dstS, WeT0, P, bm[0], agg);
    node_mfma<32, 64><<<dim3(NB, 1), 256, 0, stream>>>(xb, agg, WsT0, bs[0], Wc[0], invdeg, f1, rd);

    // layer 1: fin=64, f=128  (CW=128, EPB=256)
    nodeP<64, 128><<<dim3(NB, 2), 256, 0, stream>>>(f1, WxT1, P);
    hipMemsetAsync(agg, 0, (size_t)NN * 128 * 4, stream);
    edge_q<128><<<EB, 256, 0, stream>>>(efS, srcS, dstS, WeT1, P, bm[1], agg);
    node_mfma<64, 128><<<dim3(NB, 2), 256, 0, stream>>>(f1, agg, WsT1, bs[1], Wc[1], invdeg, f2, rd);

    // layer 2: fin=128, f=128  (CW=128, EPB=256)
    nodeP<128, 128><<<dim3(NB, 2), 256, 0, stream>>>(f2, WxT2, P);
    hipMemsetAsync(agg, 0, (size_t)NN * 128 * 4, stream);
    edge_q<128><<<EB, 256, 0, stream>>>(efS, srcS, dstS, WeT2, P, bm[2], agg);
    node_mfma<128, 128><<<dim3(NB, 2), 256, 0, stream>>>(f2, agg, WsT2, bs[2], Wc[2], invdeg, f3, rd);

    // layer 3: fin=128, f=256  (CW=128, WPG=2, EPB=128)
    nodeP<128, 256><<<dim3(NB, 4), 256, 0, stream>>>(f3, WxT3, P);
    hipMemsetAsync(agg, 0, (size_t)NN * 256 * 4, stream);
    edge_q<256><<<EE / 128, 256, 0, stream>>>(efS, srcS, dstS, WeT3, P, bm[3], agg);
    node_mfma<128, 256><<<dim3(NB, 4), 256, 0, stream>>>(f3, agg, WsT3, bs[3], Wc[3], invdeg, f4, rd);

    // final per-graph mean of accumulated classifier dots
    score_reduce<<<SCB, 256, 0, stream>>>(rd, gid, invg, score);
}

// Round 12
// 706.089 us; speedup vs baseline: 1.0710x; 1.0710x over previous
//
#include <hip/hip_runtime.h>

#define NN 50000
#define EE 800000
#define GG 512
#define NP 50048   // NN padded to multiple of 64
#define EB 3125    // edge blocks of 256
#define SCB 196    // scan blocks of 256 covering NN

typedef short bf16x8 __attribute__((ext_vector_type(8)));
typedef float floatx4 __attribute__((ext_vector_type(4)));

__device__ inline unsigned short f2b(float f) {
    unsigned u = __float_as_uint(f);
    unsigned r = (u + 0x7fffu + ((u >> 16) & 1u)) >> 16;
    return (unsigned short)r;
}
__device__ inline float b2f(unsigned short b) {
    return __uint_as_float(((unsigned)b) << 16);
}

// ---------------- fused conversion: x and ef -> bf16 ----------------

__global__ void conv_all(const float* __restrict__ x, unsigned short* __restrict__ xb, long n8x,
                         const float* __restrict__ ef, unsigned short* __restrict__ efB, long n8e) {
    long i = (long)blockIdx.x * blockDim.x + threadIdx.x;
    const float* s;
    unsigned short* d;
    long idx;
    if (i < n8x) { s = x; d = xb; idx = i; }
    else if (i < n8x + n8e) { s = ef; d = efB; idx = i - n8x; }
    else return;
    float4 a = ((const float4*)s)[2 * idx];
    float4 b = ((const float4*)s)[2 * idx + 1];
    unsigned short o[8] = {f2b(a.x), f2b(a.y), f2b(a.z), f2b(a.w),
                           f2b(b.x), f2b(b.y), f2b(b.z), f2b(b.w)};
    ((uint4*)d)[idx] = *(uint4*)o;
}

// ---------------- fused weight transpose: 12 matrices in one launch ----------------

struct TpD { const float* W; unsigned short* WT; int K, F, Kp, rowOff; };
struct TpTab { TpD d[12]; };

__global__ void tp_all(TpTab t) {
    TpD dd = t.d[blockIdx.y];
    int f = blockIdx.x;
    if (f >= dd.F) return;
    for (int k = threadIdx.x; k < dd.Kp; k += blockDim.x)
        dd.WT[(size_t)f * dd.Kp + k] =
            (k < dd.K) ? f2b(dd.W[(size_t)(dd.rowOff + k) * dd.F + f]) : (unsigned short)0;
}

// ---------------- sort pipeline ----------------

__global__ void hist_cnt(const int* __restrict__ dst, int* __restrict__ hist,
                         const int* __restrict__ gid, float* __restrict__ gcnt) {
    int b = blockIdx.x;
    if (b < EB) {
        int e = b * 256 + threadIdx.x;
        if (e < EE) atomicAdd(&hist[dst[e]], 1);
    } else {
        int n = (b - EB) * 256 + threadIdx.x;
        if (n < NN) atomicAdd(&gcnt[gid[n]], 1.0f);
    }
}

// 3-phase exclusive scan of hist -> cursor
__global__ void scanA(const int* __restrict__ hist, int* __restrict__ bsum) {
    __shared__ int sb[256];
    int idx = blockIdx.x * 256 + threadIdx.x;
    sb[threadIdx.x] = (idx < NN) ? hist[idx] : 0;
    __syncthreads();
    for (int off = 128; off > 0; off >>= 1) {
        if (threadIdx.x < off) sb[threadIdx.x] += sb[threadIdx.x + off];
        __syncthreads();
    }
    if (threadIdx.x == 0) bsum[blockIdx.x] = sb[0];
}

__global__ void scanB(const int* __restrict__ bsum, int* __restrict__ boff) {
    __shared__ int sb[256];
    int t = threadIdx.x;
    int v = (t < SCB) ? bsum[t] : 0;
    sb[t] = v;
    __syncthreads();
    for (int off = 1; off < 256; off <<= 1) {
        int u = (t >= off) ? sb[t - off] : 0;
        __syncthreads();
        sb[t] += u;
        __syncthreads();
    }
    if (t < SCB) boff[t] = sb[t] - v;
}

// scanC + finalize_init fused: cursor, invdeg, invg, score-bias init in one sweep
__global__ void scanC(const int* __restrict__ hist, const int* __restrict__ boff,
                      int* __restrict__ cursor, float* __restrict__ invdeg,
                      float* __restrict__ gcnt, float* __restrict__ score,
                      const float* __restrict__ bc0, const float* __restrict__ bc1,
                      const float* __restrict__ bc2, const float* __restrict__ bc3) {
    __shared__ int sb[256];
    int t = threadIdx.x;
    int idx = blockIdx.x * 256 + t;
    int v = (idx < NN) ? hist[idx] : 0;
    sb[t] = v;
    __syncthreads();
    for (int off = 1; off < 256; off <<= 1) {
        int u = (t >= off) ? sb[t - off] : 0;
        __syncthreads();
        sb[t] += u;
        __syncthreads();
    }
    if (idx < NN) {
        cursor[idx] = boff[blockIdx.x] + sb[t] - v;
        invdeg[idx] = 1.0f / fmaxf((float)v, 1.0f);
    }
    if (idx < GG) {
        float c = gcnt[idx];
        gcnt[idx] = 1.0f / fmaxf(c, 1.0f);
        score[idx] = (c > 0.0f) ? (bc0[0] + bc1[0] + bc2[0] + bc3[0]) : 0.0f;
    }
}

// scatter + ef gather fused: coalesced read of efB[e], scattered write to efS[p]
__global__ void scatter_kernel(const int* __restrict__ src, const int* __restrict__ dst,
                               int* __restrict__ cursor, const unsigned short* __restrict__ efB,
                               int* __restrict__ srcS, int* __restrict__ dstS,
                               unsigned short* __restrict__ efS) {
    int e = blockIdx.x * blockDim.x + threadIdx.x;
    if (e < EE) {
        int d = dst[e];
        int p = atomicAdd(&cursor[d], 1);
        srcS[p] = src[e];
        dstS[p] = d;
        const uint4* s = (const uint4*)&efB[(size_t)e * 16];
        uint4* dd = (uint4*)&efS[(size_t)p * 16];
        dd[0] = s[0];
        dd[1] = s[1];
    }
}

// ---------------- nodeP: P = feat @ WmX ----------------

template<int FIN, int F>
__global__ __launch_bounds__(256)
void nodeP(const unsigned short* __restrict__ featB, const unsigned short* __restrict__ WxT,
           unsigned short* __restrict__ P)
{
    const int tid = threadIdx.x;
    const int w   = tid >> 6;
    const int l   = tid & 63;
    const int l16 = l & 15;
    const int q   = l >> 4;
    const int cb  = blockIdx.y * 64;
    const int nb  = blockIdx.x * 64;
    const int row = nb + w * 16 + l16;

    floatx4 acc[4];
    #pragma unroll
    for (int nt = 0; nt < 4; ++nt) acc[nt] = (floatx4){0.f, 0.f, 0.f, 0.f};

    #pragma unroll
    for (int kb = 0; kb < FIN; kb += 32) {
        bf16x8 a = *(const bf16x8*)&featB[(size_t)row * FIN + kb + q * 8];
        #pragma unroll
        for (int nt = 0; nt < 4; ++nt) {
            bf16x8 b = *(const bf16x8*)&WxT[(size_t)(cb + nt * 16 + l16) * FIN + kb + q * 8];
            acc[nt] = __builtin_amdgcn_mfma_f32_16x16x32_bf16(a, b, acc[nt], 0, 0, 0);
        }
    }

    #pragma unroll
    for (int nt = 0; nt < 4; ++nt)
        #pragma unroll
        for (int r = 0; r < 4; ++r) {
            int ro = nb + w * 16 + q * 4 + r;
            P[(size_t)ro * F + cb + nt * 16 + l16] = f2b(acc[nt][r]);
        }
}

// ---------------- edge kernel (R10-proven shape): relu(efS@WmE + P[src] + bm)
// -> per-wave segmented reduce over sorted dst. CW=128 (2 cols/lane) or 64 (scalar).
// Per-strip P-gather after the MFMAs, full 16-row transpose, spill-free (VGPR 64).
// LDS wave-private: NO barriers. ----------------

template<int F>
__global__ __launch_bounds__(256)
void edge_q(const unsigned short* __restrict__ efS,
            const int* __restrict__ srcS, const int* __restrict__ dstS,
            const unsigned short* __restrict__ WeT, const unsigned short* __restrict__ P,
            const float* __restrict__ bm, float* __restrict__ agg)
{
    constexpr int CW  = (F >= 128) ? 128 : 64;  // cols per wave
    constexpr int WPG = F / CW;                 // waves per 64-edge subtile (1 or 2)
    constexpr int NT  = CW / 16;
    constexpr int EPB = 64 * (4 / WPG);         // edges per block (256 or 128)
    constexpr int RS  = (CW == 128) ? 132 : 68; // red row stride (bank-safe)

    __shared__ __align__(16) float red[4][16 * RS];

    const int tid = threadIdx.x;
    const int w   = tid >> 6;
    const int l   = tid & 63;
    const int l16 = l & 15;
    const int q   = l >> 4;
    const int sub = w / WPG;
    const int cb  = (w % WPG) * CW;
    const int be  = blockIdx.x * EPB + sub * 64;

    const int dreg = dstS[be + l];
    const int sreg = srcS[be + l];

    const bf16x8 ZV = {0, 0, 0, 0, 0, 0, 0, 0};

    // B fragments: WmE^T [F][32] (rows 16..31 zero-padded)
    bf16x8 bfr[NT];
    #pragma unroll
    for (int nt = 0; nt < NT; ++nt)
        bfr[nt] = *(const bf16x8*)&WeT[(size_t)(cb + nt * 16 + l16) * 32 + q * 8];

    if constexpr (CW == 128) {
        float2 bmv;
        bmv.x = bm[cb + 2 * l];
        bmv.y = bm[cb + 2 * l + 1];

        int cur_d = -1;
        float2 csum = {0.f, 0.f};
        bool from_start = false;

        #pragma unroll
        for (int mt = 0; mt < 4; ++mt) {
            bf16x8 a = ZV;
            if (q < 2) a = *(const bf16x8*)&efS[(size_t)(be + mt * 16 + l16) * 16 + q * 8];
            floatx4 acc[NT];
            #pragma unroll
            for (int nt = 0; nt < NT; ++nt)
                acc[nt] = __builtin_amdgcn_mfma_f32_16x16x32_bf16(
                    a, bfr[nt], (floatx4){0.f, 0.f, 0.f, 0.f}, 0, 0, 0);

            unsigned pvv[16];
            #pragma unroll
            for (int r = 0; r < 16; ++r) {
                int sr = __shfl(sreg, mt * 16 + r);
                pvv[r] = *(const unsigned*)&P[(size_t)sr * F + cb + 2 * l];
            }

            #pragma unroll
            for (int nt = 0; nt < NT; ++nt)
                #pragma unroll
                for (int r4 = 0; r4 < 4; ++r4)
                    red[w][(q * 4 + r4) * RS + nt * 16 + l16] = acc[nt][r4];

            #pragma unroll
            for (int r = 0; r < 16; ++r) {
                int gr = mt * 16 + r;
                int d = __shfl(dreg, gr);
                float2 qv = *(const float2*)&red[w][r * RS + 2 * l];
                float2 v;
                v.x = fmaxf(qv.x + __uint_as_float(pvv[r] << 16)         + bmv.x, 0.f);
                v.y = fmaxf(qv.y + __uint_as_float(pvv[r] & 0xffff0000u) + bmv.y, 0.f);
                if (gr == 0) {
                    cur_d = d; csum = v; from_start = true;
                } else if (d != cur_d) {
                    float* ap = &agg[(size_t)cur_d * F + cb + 2 * l];
                    if (from_start) { atomicAdd(ap, csum.x); atomicAdd(ap + 1, csum.y); }
                    else            { *(float2*)ap = csum; }
                    cur_d = d; csum = v; from_start = false;
                } else {
                    csum.x += v.x; csum.y += v.y;
                }
            }
        }
        float* ap = &agg[(size_t)cur_d * F + cb + 2 * l];
        atomicAdd(ap, csum.x);
        atomicAdd(ap + 1, csum.y);
    } else {
        const float bmv = bm[cb + l];

        int cur_d = -1;
        float csum = 0.f;
        bool from_start = false;

        #pragma unroll
        for (int mt = 0; mt < 4; ++mt) {
            bf16x8 a = ZV;
            if (q < 2) a = *(const bf16x8*)&efS[(size_t)(be + mt * 16 + l16) * 16 + q * 8];
            floatx4 acc[NT];
            #pragma unroll
            for (int nt = 0; nt < NT; ++nt)
                acc[nt] = __builtin_amdgcn_mfma_f32_16x16x32_bf16(
                    a, bfr[nt], (floatx4){0.f, 0.f, 0.f, 0.f}, 0, 0, 0);

            float pv[16];
            #pragma unroll
            for (int r = 0; r < 16; ++r) {
                int sr = __shfl(sreg, mt * 16 + r);
                pv[r] = b2f(P[(size_t)sr * F + cb + l]);
            }

            #pragma unroll
            for (int nt = 0; nt < NT; ++nt)
                #pragma unroll
                for (int r4 = 0; r4 < 4; ++r4)
                    red[w][(q * 4 + r4) * RS + nt * 16 + l16] = acc[nt][r4];

            #pragma unroll
            for (int r = 0; r < 16; ++r) {
                int gr = mt * 16 + r;
                int d = __shfl(dreg, gr);
                float v = fmaxf(red[w][r * RS + l] + pv[r] + bmv, 0.f);
                if (gr == 0) {
                    cur_d = d; csum = v; from_start = true;
                } else if (d != cur_d) {
                    float* ap = &agg[(size_t)cur_d * F + cb + l];
                    if (from_start) atomicAdd(ap, csum);
                    else *ap = csum;
                    cur_d = d; csum = v; from_start = false;
                } else {
                    csum += v;
                }
            }
        }
        atomicAdd(&agg[(size_t)cur_d * F + cb + l], csum);
    }
}

// ---------------- node MFMA GEMM: feat' = relu(agg*invdeg + feat@Ws + bs);
// per-node classifier dot accumulated into rd[n] ----------------

template<int FIN, int F>
__global__ __launch_bounds__(256)
void node_mfma(const unsigned short* __restrict__ featB, const float* __restrict__ agg,
               const unsigned short* __restrict__ WsT, const float* __restrict__ bs,
               const float* __restrict__ Wc, const float* __restrict__ invdeg,
               unsigned short* __restrict__ fout, float* __restrict__ rd)
{
    const int tid = threadIdx.x;
    const int w   = tid >> 6;
    const int l   = tid & 63;
    const int l16 = l & 15;
    const int q   = l >> 4;
    const int cb  = blockIdx.y * 64;
    const int nb  = blockIdx.x * 64;
    const int row = nb + w * 16 + l16;

    floatx4 acc[4];
    #pragma unroll
    for (int nt = 0; nt < 4; ++nt) acc[nt] = (floatx4){0.f, 0.f, 0.f, 0.f};

    #pragma unroll
    for (int kb = 0; kb < FIN; kb += 32) {
        bf16x8 a = *(const bf16x8*)&featB[(size_t)row * FIN + kb + q * 8];
        #pragma unroll
        for (int nt = 0; nt < 4; ++nt) {
            bf16x8 b = *(const bf16x8*)&WsT[(size_t)(cb + nt * 16 + l16) * FIN + kb + q * 8];
            acc[nt] = __builtin_amdgcn_mfma_f32_16x16x32_bf16(a, b, acc[nt], 0, 0, 0);
        }
    }

    float wcv[4], bsv[4];
    #pragma unroll
    for (int nt = 0; nt < 4; ++nt) {
        wcv[nt] = Wc[cb + nt * 16 + l16];
        bsv[nt] = bs[cb + nt * 16 + l16];
    }

    #pragma unroll
    for (int r = 0; r < 4; ++r) {
        int n = nb + w * 16 + q * 4 + r;
        bool valid = n < NN;
        float idg = valid ? invdeg[n] : 0.f;
        float s = 0.f;
        #pragma unroll
        for (int nt = 0; nt < 4; ++nt) {
            int col = cb + nt * 16 + l16;
            float av = valid ? agg[(size_t)n * F + col] : 0.f;
            float v = fmaxf(acc[nt][r] + av * idg + bsv[nt], 0.f);
            if (valid) fout[(size_t)n * F + col] = f2b(v);
            s += v * wcv[nt];
        }
        s += __shfl_xor(s, 1);
        s += __shfl_xor(s, 2);
        s += __shfl_xor(s, 4);
        s += __shfl_xor(s, 8);
        if (valid && l16 == 0) atomicAdd(&rd[n], s);
    }
}

// ---------------- final: score[g] += invg[g] * segmented-sum(rd) over sorted gid ----------------

__global__ void score_reduce(const float* __restrict__ rd, const int* __restrict__ gid,
                             const float* __restrict__ invg, float* __restrict__ score) {
    int n = blockIdx.x * blockDim.x + threadIdx.x;
    int l = threadIdx.x & 63;
    bool valid = n < NN;
    int g = valid ? gid[n] : -1;
    float v = valid ? rd[n] : 0.f;
    #pragma unroll
    for (int off = 1; off < 64; off <<= 1) {
        float vo = __shfl_up(v, off);
        int go = __shfl_up(g, off);
        if (l >= off && go == g) v += vo;
    }
    int gn = __shfl_down(g, 1);
    bool tail = (l == 63) || (gn != g);
    if (valid && tail) atomicAdd(&score[g], v * invg[g]);
}

// ---------------- host ----------------

extern "C" void kernel_launch(void* const* d_in, const int* in_sizes, int n_in,
                              void* d_out, int out_size, void* d_ws, size_t ws_size,
                              hipStream_t stream) {
    const float* x   = (const float*)d_in[0];
    const float* ef  = (const float*)d_in[1];
    const int*   src = (const int*)d_in[2];
    const int*   dst = (const int*)d_in[3];
    const int*   gid = (const int*)d_in[4];
    const float *Wm[4], *bm[4], *Ws[4], *bs[4], *Wc[4], *bc[4];
    for (int i = 0; i < 4; ++i) {
        Wm[i] = (const float*)d_in[5 + 6 * i];
        bm[i] = (const float*)d_in[6 + 6 * i];
        Ws[i] = (const float*)d_in[7 + 6 * i];
        bs[i] = (const float*)d_in[8 + 6 * i];
        Wc[i] = (const float*)d_in[9 + 6 * i];
        bc[i] = (const float*)d_in[10 + 6 * i];
    }

    char* w = (char*)d_ws;
    float* agg = (float*)w;                  w += (size_t)NN * 256 * 4;
    unsigned short* xb  = (unsigned short*)w; w += (size_t)NP * 32 * 2;
    unsigned short* f1  = (unsigned short*)w; w += (size_t)NP * 64 * 2;
    unsigned short* f2  = (unsigned short*)w; w += (size_t)NP * 128 * 2;
    unsigned short* f3  = (unsigned short*)w; w += (size_t)NP * 128 * 2;
    unsigned short* f4  = (unsigned short*)w; w += (size_t)NP * 256 * 2;
    unsigned short* P   = (unsigned short*)w; w += (size_t)NP * 256 * 2;
    unsigned short* efB = (unsigned short*)w; w += (size_t)EE * 16 * 2;
    unsigned short* efS = (unsigned short*)w; w += (size_t)EE * 16 * 2;
    unsigned short* WxT0 = (unsigned short*)w; w += (size_t)64 * 32 * 2;
    unsigned short* WxT1 = (unsigned short*)w; w += (size_t)128 * 64 * 2;
    unsigned short* WxT2 = (unsigned short*)w; w += (size_t)128 * 128 * 2;
    unsigned short* WxT3 = (unsigned short*)w; w += (size_t)256 * 128 * 2;
    unsigned short* WeT0 = (unsigned short*)w; w += (size_t)64 * 32 * 2;
    unsigned short* WeT1 = (unsigned short*)w; w += (size_t)128 * 32 * 2;
    unsigned short* WeT2 = (unsigned short*)w; w += (size_t)128 * 32 * 2;
    unsigned short* WeT3 = (unsigned short*)w; w += (size_t)256 * 32 * 2;
    unsigned short* WsT0 = (unsigned short*)w; w += (size_t)64 * 32 * 2;
    unsigned short* WsT1 = (unsigned short*)w; w += (size_t)128 * 64 * 2;
    unsigned short* WsT2 = (unsigned short*)w; w += (size_t)128 * 128 * 2;
    unsigned short* WsT3 = (unsigned short*)w; w += (size_t)256 * 128 * 2;
    float* invdeg = (float*)w;               w += (size_t)NN * 4;
    // contiguous zero-block: invg | rd | hist  (single memset)
    float* invg   = (float*)w;               w += (size_t)GG * 4;
    float* rd     = (float*)w;               w += (size_t)NN * 4;
    int* hist   = (int*)w;                   w += (size_t)(NN + 1) * 4;
    int* srcS   = (int*)w;                   w += (size_t)EE * 4;
    int* dstS   = (int*)w;                   w += (size_t)EE * 4;
    int* bsum   = (int*)w;                   w += (size_t)SCB * 4;
    int* boff   = (int*)w;                   w += (size_t)SCB * 4;
    int* cursor = (int*)w;                   w += (size_t)NN * 4;
    float* score = (float*)d_out;

    // ---- conversions / weight prep (fused launches) ----
    const long n8x = (long)NN * 32 / 8, n8e = (long)EE * 16 / 8;
    conv_all<<<(n8x + n8e + 255) / 256, 256, 0, stream>>>(x, xb, n8x, ef, efB, n8e);

    TpTab tt;
    tt.d[0]  = {Wm[0], WxT0,  32,  64,  32,   0};
    tt.d[1]  = {Wm[1], WxT1,  64, 128,  64,   0};
    tt.d[2]  = {Wm[2], WxT2, 128, 128, 128,   0};
    tt.d[3]  = {Wm[3], WxT3, 128, 256, 128,   0};
    tt.d[4]  = {Wm[0], WeT0,  16,  64,  32,  32};
    tt.d[5]  = {Wm[1], WeT1,  16, 128,  32,  64};
    tt.d[6]  = {Wm[2], WeT2,  16, 128,  32, 128};
    tt.d[7]  = {Wm[3], WeT3,  16, 256,  32, 128};
    tt.d[8]  = {Ws[0], WsT0,  32,  64,  32,   0};
    tt.d[9]  = {Ws[1], WsT1,  64, 128,  64,   0};
    tt.d[10] = {Ws[2], WsT2, 128, 128, 128,   0};
    tt.d[11] = {Ws[3], WsT3, 128, 256, 128,   0};
    tp_all<<<dim3(256, 12), 256, 0, stream>>>(tt);

    // ---- sort edges by dst ----
    hipMemsetAsync(invg, 0, (size_t)(GG + NN + NN + 1) * 4, stream);  // invg|rd|hist
    hist_cnt<<<EB + SCB, 256, 0, stream>>>(dst, hist, gid, invg);
    scanA<<<SCB, 256, 0, stream>>>(hist, bsum);
    scanB<<<1, 256, 0, stream>>>(bsum, boff);
    scanC<<<SCB, 256, 0, stream>>>(hist, boff, cursor, invdeg, invg, score,
                                   bc[0], bc[1], bc[2], bc[3]);
    scatter_kernel<<<EB, 256, 0, stream>>>(src, dst, cursor, efB, srcS, dstS, efS);

    const int NB = NP / 64;            // 782

    // layer 0: fin=32, f=64  (CW=64, EPB=256)
    nodeP<32, 64><<<dim3(NB, 1), 256, 0, stream>>>(xb, WxT0, P);
    hipMemsetAsync(agg, 0, (size_t)NN * 64 * 4, stream);
    edge_q<64><<<EB, 256, 0, stream>>>(efS, srcS, dstS, WeT0, P, bm[0], agg);
    node_mfma<32, 64><<<dim3(NB, 1), 256, 0, stream>>>(xb, agg, WsT0, bs[0], Wc[0], invdeg, f1, rd);

    // layer 1: fin=64, f=128  (CW=128, EPB=256)
    nodeP<64, 128><<<dim3(NB, 2), 256, 0, stream>>>(f1, WxT1, P);
    hipMemsetAsync(agg, 0, (size_t)NN * 128 * 4, stream);
    edge_q<128><<<EB, 256, 0, stream>>>(efS, srcS, dstS, WeT1, P, bm[1], agg);
    node_mfma<64, 128><<<dim3(NB, 2), 256, 0, stream>>>(f1, agg, WsT1, bs[1], Wc[1], invdeg, f2, rd);

    // layer 2: fin=128, f=128  (CW=128, EPB=256)
    nodeP<128, 128><<<dim3(NB, 2), 256, 0, stream>>>(f2, WxT2, P);
    hipMemsetAsync(agg, 0, (size_t)NN * 128 * 4, stream);
    edge_q<128><<<EB, 256, 0, stream>>>(efS, srcS, dstS, WeT2, P, bm[2], agg);
    node_mfma<128, 128><<<dim3(NB, 2), 256, 0, stream>>>(f2, agg, WsT2, bs[2], Wc[2], invdeg, f3, rd);

    // layer 3: fin=128, f=256  (CW=128, WPG=2, EPB=128)
    nodeP<128, 256><<<dim3(NB, 4), 256, 0, stream>>>(f3, WxT3, P);
    hipMemsetAsync(agg, 0, (size_t)NN * 256 * 4, stream);
    edge_q<256><<<EE / 128, 256, 0, stream>>>(efS, srcS, dstS, WeT3, P, bm[3], agg);
    node_mfma<128, 256><<<dim3(NB, 4), 256, 0, stream>>>(f3, agg, WsT3, bs[3], Wc[3], invdeg, f4, rd);

    // final per-graph mean of accumulated classifier dots
    score_reduce<<<SCB, 256, 0, stream>>>(rd, gid, invg, score);
}